// Round 4
// baseline (11656.715 us; speedup 1.0000x reference)
//
#include <hip/hip_runtime.h>
#include <hip/hip_cooperative_groups.h>

namespace cg = cooperative_groups;

// R14: cooperative weight-stationary BiLSTM, slot-barrier + single-wave tail.
// 256 WGs x 512 thr (1/CU). WG = (dir, cell-slice): 4 cells x 16 gate rows,
// all 32 batches. Barrier: per-WG epoch slot (64B apart) in d_ws, release
// store by wave 0; detection = 128 threads poll one slot each (relaxed,
// agent scope = sc1, bypasses L2). h exchange through `out` (sc1 write-
// through stores, normal cached reads at fresh addresses -> L2 miss -> LLC).
// No cache-wide fences anywhere in the loop; weights/x stay L2-resident.
// Tail (pointwise + publish + flag) is wave-0-only; waves 1-7 run ahead
// into the next step's x staging so publish latency is hidden.

#define Bv 32
#define Tv 512
#define Dv 512
#define Hv 512
#define XS 520            // x LDS row stride (floats)
#define HS 520            // h LDS row stride
#define PUN 16896         // union: max(32*HS=16640, 512*33=16896)

__device__ __forceinline__ float sigmf_(float x) { return 1.0f / (1.0f + __expf(-x)); }
__device__ __forceinline__ float tanhf_(float x) { return 2.0f / (1.0f + __expf(-2.0f * x)) - 1.0f; }

__global__ __launch_bounds__(512, 2) void bilstm_coop4(
    const float* __restrict__ x, const int* __restrict__ lengths,
    const float* __restrict__ Wih_f, const float* __restrict__ Whh_f,
    const float* __restrict__ bih_f, const float* __restrict__ bhh_f,
    const float* __restrict__ Wih_b, const float* __restrict__ Whh_b,
    const float* __restrict__ bih_b, const float* __restrict__ bhh_b,
    float* __restrict__ out, unsigned int* __restrict__ cnt)  // cnt: 256 slots x 16 uints
{
    __shared__ float xb[Bv * XS];      // x_t stage
    __shared__ float hu[PUN];          // h stage / partial union
    __shared__ float gates[16 * 33];
    __shared__ float bias_s[16];

    const int tid  = threadIdx.x;
    const int w    = blockIdx.x;
    const int wave = tid >> 6;
    const int lane = tid & 63;

    // blockIdx -> XCD is (w & 7). XCDs 0..3 = dir 0, XCDs 4..7 = dir 1.
    const int xcd  = w & 7;
    const int dir  = xcd >> 2;
    const int slot = w >> 3;                    // 0..31
    const int cs   = (xcd & 3) * 32 + slot;     // 0..127 cell-slice within dir
    const int c0   = cs * 4;

    unsigned int* myslot = cnt + (size_t)(dir * 128 + cs) * 16;   // own 64B line

    const float* Wih = dir ? Wih_b : Wih_f;
    const float* Whh = dir ? Whh_b : Whh_f;
    const float* bih = dir ? bih_b : bih_f;
    const float* bhh = dir ? bhh_b : bhh_f;

    // ---- prologue ----
    if (tid == 0) *myslot = 0u;      // own slot; visible after grid.sync
    if (tid < 16) {
        int g = tid >> 2, cj = tid & 3;
        int rg = g * Hv + c0 + cj;
        bias_s[tid] = bih[rg] + bhh[rg];
    }
    cg::this_grid().sync();   // once per launch: slots zeroed + visible

    // thread tile: 4 gate-rows (rpos) x 8 batches (bpos) x 32-float k-segment
    const int pos  = tid >> 5;      // 0..15
    const int kseg = tid & 31;      // 0..31
    const int rpos = pos >> 2;      // gate 0..3
    const int bpos = pos & 3;       // batch block of 8

    // ---- hoist step-invariant Whh slice into registers (16 x float4) ----
    float4 whr[4][4];
    #pragma unroll
    for (int j = 0; j < 4; ++j)
        #pragma unroll
        for (int i = 0; i < 4; ++i)
            whr[j][i] = *(const float4*)(Whh + (size_t)(rpos * Hv + c0 + i) * Dv
                                             + (j * 32 + kseg) * 4);

    // ---- wave-0 persistent per-batch state (lane = batch) ----
    float4 cst_r = make_float4(0.f, 0.f, 0.f, 0.f);
    int len_r = 0;
    if (wave == 0 && lane < 32) len_r = lengths[lane];

    for (int s = 0; s < Tv; ++s) {
        const int t = dir ? (Tv - 1 - s) : s;

        // ---- 1. stage x_t (normal cached loads; shared via XCD L2) ----
        #pragma unroll
        for (int j = 0; j < 8; ++j) {
            int F  = tid + j * 512;
            int bl = F >> 7, cf = F & 127;
            *(float4*)(xb + bl * XS + cf * 4) =
                *(const float4*)(x + ((size_t)bl * Tv + t) * Dv + cf * 4);
        }
        __syncthreads();   // [A] xb ready (also rejoins wave 0 from prev tail)

        // ---- 2. x-part GEMM (Wih L2-resident) ----
        float acc[4][8];
        #pragma unroll
        for (int i = 0; i < 4; ++i)
            #pragma unroll
            for (int ib = 0; ib < 8; ++ib) acc[i][ib] = 0.0f;

        #pragma unroll
        for (int j = 0; j < 4; ++j) {
            const int col = (j * 32 + kseg) * 4;
            float4 wv[4];
            #pragma unroll
            for (int i = 0; i < 4; ++i)
                wv[i] = *(const float4*)(Wih + (size_t)(rpos * Hv + c0 + i) * Dv + col);
            float4 xv[8];
            #pragma unroll
            for (int ib = 0; ib < 8; ++ib)
                xv[ib] = *(const float4*)(xb + (bpos * 8 + ib) * XS + col);
            #pragma unroll
            for (int i = 0; i < 4; ++i)
                #pragma unroll
                for (int ib = 0; ib < 8; ++ib)
                    acc[i][ib] += wv[i].x * xv[ib].x + wv[i].y * xv[ib].y
                                + wv[i].z * xv[ib].z + wv[i].w * xv[ib].w;
        }

        // ---- 3. WAIT: 128 threads poll one slot each (parallel, no fence) ----
        if (s > 0 && tid < 128) {
            const unsigned int tgt = (unsigned int)s;
            const unsigned int* sl = cnt + (size_t)(dir * 128 + tid) * 16;
            while (__hip_atomic_load(sl, __ATOMIC_RELAXED,
                                     __HIP_MEMORY_SCOPE_AGENT) < tgt)
                __builtin_amdgcn_s_sleep(1);
        }
        __syncthreads();   // [B] barrier passed

        // ---- 4. stage h_{s-1} from out (fresh addresses -> L2 miss -> LLC) ----
        if (s == 0) {
            #pragma unroll
            for (int j = 0; j < 8; ++j) {
                int F  = tid + j * 512;
                int bl = F >> 7, cf = F & 127;
                *(float4*)(hu + bl * HS + cf * 4) = make_float4(0.f, 0.f, 0.f, 0.f);
            }
        } else {
            const int tp = dir ? (t + 1) : (t - 1);
            #pragma unroll
            for (int j = 0; j < 8; ++j) {
                int F  = tid + j * 512;
                int bl = F >> 7, cf = F & 127;
                *(float4*)(hu + bl * HS + cf * 4) =
                    *(const float4*)(out + ((size_t)bl * Tv + tp) * (2 * Hv)
                                         + dir * Hv + cf * 4);
            }
        }
        __syncthreads();   // [C] hu ready

        // hold-values for masked batches (wave 0, before hu is overwritten)
        float4 hpv = make_float4(0.f, 0.f, 0.f, 0.f);
        if (wave == 0 && lane < 32)
            hpv = *(const float4*)(hu + lane * HS + c0);

        // ---- 5. h-part GEMM: pure LDS + register weights ----
        #pragma unroll
        for (int j = 0; j < 4; ++j) {
            const int col = (j * 32 + kseg) * 4;
            float4 hv[8];
            #pragma unroll
            for (int ib = 0; ib < 8; ++ib)
                hv[ib] = *(const float4*)(hu + (bpos * 8 + ib) * HS + col);
            #pragma unroll
            for (int i = 0; i < 4; ++i)
                #pragma unroll
                for (int ib = 0; ib < 8; ++ib)
                    acc[i][ib] += whr[j][i].x * hv[ib].x + whr[j][i].y * hv[ib].y
                                + whr[j][i].z * hv[ib].z + whr[j][i].w * hv[ib].w;
        }
        __syncthreads();   // [D] hu reads (and hpv) done; alias as partial[512][33]

        // ---- 6. partial dump ----
        float* part = hu;
        #pragma unroll
        for (int i = 0; i < 4; ++i)
            #pragma unroll
            for (int ib = 0; ib < 8; ++ib) {
                int row = (rpos * 4 + i) * 32 + (bpos * 8 + ib);
                part[row * 33 + kseg] = acc[i][ib];
            }
        __syncthreads();   // [E]

        // ---- 7. final reduce + bias -> gates ----
        {
            const float* pr = part + tid * 33;
            float s0 = 0.f, s1 = 0.f, s2 = 0.f, s3 = 0.f;
            #pragma unroll
            for (int m = 0; m < 32; m += 4) {
                s0 += pr[m + 0]; s1 += pr[m + 1]; s2 += pr[m + 2]; s3 += pr[m + 3];
            }
            int lr = tid >> 5, bl = tid & 31;
            gates[lr * 33 + bl] = ((s0 + s1) + (s2 + s3)) + bias_s[lr];
        }
        __syncthreads();   // [F] gates ready — waves 1..7 sprint to next x-stage

        // ---- 8. TAIL (wave 0 only): pointwise, publish, flag ----
        if (wave == 0 && lane < 32) {
            const int bl = lane;
            float hn[4], cn[4];
            #pragma unroll
            for (int cj = 0; cj < 4; ++cj) {
                float gi = sigmf_(gates[(0 * 4 + cj) * 33 + bl]);
                float gf = sigmf_(gates[(1 * 4 + cj) * 33 + bl]);
                float gg = tanhf_(gates[(2 * 4 + cj) * 33 + bl]);
                float go = sigmf_(gates[(3 * 4 + cj) * 33 + bl]);
                float cold = (cj == 0) ? cst_r.x : (cj == 1) ? cst_r.y
                           : (cj == 2) ? cst_r.z : cst_r.w;
                cn[cj] = gf * cold + gi * gg;
                hn[cj] = go * tanhf_(cn[cj]);
            }
            const bool v = (t < len_r);
            float4 ho;
            ho.x = v ? hn[0] : hpv.x;  cst_r.x = v ? cn[0] : cst_r.x;
            ho.y = v ? hn[1] : hpv.y;  cst_r.y = v ? cn[1] : cst_r.y;
            ho.z = v ? hn[2] : hpv.z;  cst_r.z = v ? cn[2] : cst_r.z;
            ho.w = v ? hn[3] : hpv.w;  cst_r.w = v ? cn[3] : cst_r.w;

            float* base = out + ((size_t)bl * Tv + t) * (2 * Hv) + dir * Hv + c0;
            __hip_atomic_store(base + 0, ho.x, __ATOMIC_RELAXED, __HIP_MEMORY_SCOPE_AGENT);
            __hip_atomic_store(base + 1, ho.y, __ATOMIC_RELAXED, __HIP_MEMORY_SCOPE_AGENT);
            __hip_atomic_store(base + 2, ho.z, __ATOMIC_RELAXED, __HIP_MEMORY_SCOPE_AGENT);
            __hip_atomic_store(base + 3, ho.w, __ATOMIC_RELAXED, __HIP_MEMORY_SCOPE_AGENT);
        }
        if (wave == 0 && lane == 0) {
            // release: waits this wave's vmcnt (all 128 h stores) then flags
            __hip_atomic_store(myslot, (unsigned int)(s + 1),
                               __ATOMIC_RELEASE, __HIP_MEMORY_SCOPE_AGENT);
        }
        // no syncthreads: next iteration's [A] rejoins wave 0
    }
}

// ---------------- fallback: R10 kernel (unchanged, correct, slow) ----------------
__global__ __launch_bounds__(1024, 1) void bilstm_simple(
    const float* __restrict__ x,
    const int* __restrict__ lengths,
    const float* __restrict__ Wih_f, const float* __restrict__ Whh_f,
    const float* __restrict__ bih_f, const float* __restrict__ bhh_f,
    const float* __restrict__ Wih_b, const float* __restrict__ Whh_b,
    const float* __restrict__ bih_b, const float* __restrict__ bhh_b,
    float* __restrict__ out)
{
    __shared__ float xh[Dv + Hv];
    __shared__ float cst[Hv];
    __shared__ float gates[4 * Hv];
    __shared__ float bias[4 * Hv];

    const int tid  = threadIdx.x;
    const int wave = tid >> 6;
    const int lane = tid & 63;
    const int dir  = blockIdx.x >> 5;
    const int b    = blockIdx.x & 31;

    const float* Wih = dir ? Wih_b : Wih_f;
    const float* Whh = dir ? Whh_b : Whh_f;
    const float* bih = dir ? bih_b : bih_f;
    const float* bhh = dir ? bhh_b : bhh_f;

    for (int i = tid; i < 4 * Hv; i += 1024) bias[i] = bih[i] + bhh[i];
    for (int i = tid; i < Hv; i += 1024) { xh[Dv + i] = 0.f; cst[i] = 0.f; }
    const int len = lengths[b];

    const float* Wbase = (lane < 32) ? Wih : Whh;
    const int koff = (lane & 31) * 16;

    for (int s = 0; s < Tv; ++s) {
        const int t = dir ? (Tv - 1 - s) : s;
        __syncthreads();
        for (int i = tid; i < Dv; i += 1024)
            xh[i] = x[((size_t)b * Tv + t) * Dv + i];
        __syncthreads();

        float4 xr0 = *(const float4*)(xh + lane * 16 + 0);
        float4 xr1 = *(const float4*)(xh + lane * 16 + 4);
        float4 xr2 = *(const float4*)(xh + lane * 16 + 8);
        float4 xr3 = *(const float4*)(xh + lane * 16 + 12);

        #pragma unroll 4
        for (int rr = 0; rr < 128; ++rr) {
            const int row = wave * 128 + rr;
            const float4* wr = (const float4*)(Wbase + (size_t)row * 512 + koff);
            const float4 w0 = wr[0], w1 = wr[1], w2 = wr[2], w3 = wr[3];
            float acc = w0.x * xr0.x + w0.y * xr0.y + w0.z * xr0.z + w0.w * xr0.w
                      + w1.x * xr1.x + w1.y * xr1.y + w1.z * xr1.z + w1.w * xr1.w
                      + w2.x * xr2.x + w2.y * xr2.y + w2.z * xr2.z + w2.w * xr2.w
                      + w3.x * xr3.x + w3.y * xr3.y + w3.z * xr3.z + w3.w * xr3.w;
            #pragma unroll
            for (int off = 32; off > 0; off >>= 1)
                acc += __shfl_xor(acc, off, 64);
            if (lane == 0) gates[row] = acc;
        }
        __syncthreads();

        if (tid < Hv) {
            const int cc = tid;
            const float gi = sigmf_(gates[0 * Hv + cc] + bias[0 * Hv + cc]);
            const float gf = sigmf_(gates[1 * Hv + cc] + bias[1 * Hv + cc]);
            const float gg = tanhf_(gates[2 * Hv + cc] + bias[2 * Hv + cc]);
            const float go = sigmf_(gates[3 * Hv + cc] + bias[3 * Hv + cc]);
            const float cn = gf * cst[cc] + gi * gg;
            const float hn = go * tanhf_(cn);
            const bool v = (t < len);
            const float hnew = v ? hn : xh[Dv + cc];
            cst[cc] = v ? cn : cst[cc];
            xh[Dv + cc] = hnew;
            out[((size_t)b * Tv + t) * (2 * Hv) + dir * Hv + cc] = hnew;
        }
    }
}

extern "C" void kernel_launch(void* const* d_in, const int* in_sizes, int n_in,
                              void* d_out, int out_size, void* d_ws, size_t ws_size,
                              hipStream_t stream) {
    (void)out_size;

    const void *xv, *len_p, *Wihf, *Whhf, *bihf, *bhhf, *Wihb, *Whhb, *bihb, *bhhb;
    if (n_in == 10 && in_sizes[9] == 8388608 && in_sizes[8] == 32) {
        // alphabetical pytree order fallback
        Whhb = d_in[0]; Whhf = d_in[1]; Wihb = d_in[2]; Wihf = d_in[3];
        bhhb = d_in[4]; bhhf = d_in[5]; bihb = d_in[6]; bihf = d_in[7];
        len_p = d_in[8]; xv = d_in[9];
    } else {
        // documented dict order
        xv = d_in[0]; len_p = d_in[1];
        Wihf = d_in[2]; Whhf = d_in[3]; bihf = d_in[4]; bhhf = d_in[5];
        Wihb = d_in[6]; Whhb = d_in[7]; bihb = d_in[8]; bhhb = d_in[9];
    }

    const float* xf  = (const float*)xv;
    const int*   lp  = (const int*)len_p;
    const float* wif = (const float*)Wihf;  const float* whf = (const float*)Whhf;
    const float* bif = (const float*)bihf;  const float* bhf = (const float*)bhhf;
    const float* wib = (const float*)Wihb;  const float* whb = (const float*)Whhb;
    const float* bib = (const float*)bihb;  const float* bhb = (const float*)bhhb;
    float* outp = (float*)d_out;
    unsigned int* cntp = (unsigned int*)d_ws;

    if (ws_size >= 256 * 16 * sizeof(unsigned int)) {   // 16 KB of slots
        void* args[12] = { &xf, &lp, &wif, &whf, &bif, &bhf,
                           &wib, &whb, &bib, &bhb, &outp, &cntp };
        hipError_t e = hipLaunchCooperativeKernel((const void*)bilstm_coop4,
                                                  dim3(256), dim3(512),
                                                  args, 0, stream);
        if (e == hipSuccess) return;
    }

    // fallback: R10 kernel
    bilstm_simple<<<dim3(64), dim3(1024), 0, stream>>>(
        xf, lp, wif, whf, bif, bhf, wib, whb, bib, bhb, outp);
}

// Round 5
// 5323.299 us; speedup vs baseline: 2.1898x; 2.1898x over previous
//
#include <hip/hip_runtime.h>
#include <hip/hip_cooperative_groups.h>

namespace cg = cooperative_groups;

// R15: cooperative weight-stationary BiLSTM, small independent barriers.
// 256 WGs x 512 thr (1/CU). WG = (dir, batch-group bg of 8 batches, 16-cell
// slice). 8 independent (dir,bg) pipelines of 32 WGs each. Per step:
//   stage x(8x512) -> x-GEMM -> wait(32 packed slots, 2 lines) ->
//   stage h(8x512, cached loads at fresh out addresses) -> h-GEMM (reg Whh)
//   -> partial reduce -> pointwise (128 thr, reg c-state) ->
//   publish h as FULL 64B lines (sc1) -> release own 4B slot.
// No RMW atomics in the loop, no cache-wide fences, weights L2-resident
// (per-XCD Wih slice 1MB via cslice-XCD mapping), Whh slice in registers.

#define Bv 32
#define Tv 512
#define Dv 512
#define Hv 512
#define XS 520            // x LDS row stride (floats)
#define HS 520            // h LDS row stride
#define PUN 16896         // dword union: max(8*HS=4160, 512*33=16896)

__device__ __forceinline__ float sigmf_(float x) { return 1.0f / (1.0f + __expf(-x)); }
__device__ __forceinline__ float tanhf_(float x) { return 2.0f / (1.0f + __expf(-2.0f * x)) - 1.0f; }

__global__ __launch_bounds__(512, 2) void bilstm_coop5(
    const float* __restrict__ x, const int* __restrict__ lengths,
    const float* __restrict__ Wih_f, const float* __restrict__ Whh_f,
    const float* __restrict__ bih_f, const float* __restrict__ bhh_f,
    const float* __restrict__ Wih_b, const float* __restrict__ Whh_b,
    const float* __restrict__ bih_b, const float* __restrict__ bhh_b,
    float* __restrict__ out, unsigned int* __restrict__ cnt)  // cnt: 8 groups x 64 uints
{
    __shared__ float xb[8 * XS];       // x_t stage (8 batches x 512)
    __shared__ float hu[PUN];          // h stage / partial union
    __shared__ float gates[64 * 9];    // [row 64][b 8] pad 9
    __shared__ float bias_s[64];

    const int tid  = threadIdx.x;
    const int w    = blockIdx.x;

    // blockIdx -> XCD is (w & 7). XCDs 0..3 = dir 0, XCDs 4..7 = dir 1.
    // cslice is XCD-local (8 per XCD) so each XCD touches only 1MB of Wih.
    const int xcd    = w & 7;
    const int slot   = w >> 3;                    // 0..31
    const int dir    = xcd >> 2;
    const int cslice = (xcd & 3) * 8 + (slot & 7);  // 0..31
    const int bg     = slot >> 3;                   // 0..3
    const int c0     = cslice * 16;                 // first of 16 cells
    const int b0     = bg * 8;                      // first of 8 batches
    const int group  = dir * 4 + bg;                // 0..7

    unsigned int* myslot = cnt + (size_t)group * 64 + cslice;  // packed 4B slots

    const float* Wih = dir ? Wih_b : Wih_f;
    const float* Whh = dir ? Whh_b : Whh_f;
    const float* bih = dir ? bih_b : bih_f;
    const float* bhh = dir ? bhh_b : bhh_f;

    // ---- prologue ----
    if (tid == 0)
        __hip_atomic_store(myslot, 0u, __ATOMIC_RELAXED, __HIP_MEMORY_SCOPE_AGENT);
    if (tid < 64) {
        int g = tid >> 4, cell = tid & 15;
        int rg = g * Hv + c0 + cell;
        bias_s[tid] = bih[rg] + bhh[rg];
    }
    cg::this_grid().sync();   // once per launch: all slots zeroed + visible

    // thread tile: pos = 4 gate-rows, all 8 batches, 32-float k-segment
    const int pos  = tid >> 5;      // 0..15 -> rows pos*4 .. pos*4+3 (of 64)
    const int kseg = tid & 31;      // 0..31

    // global W row index for this thread's 4 rows
    int wrow[4];
    #pragma unroll
    for (int i = 0; i < 4; ++i) {
        int r = pos * 4 + i;                 // 0..63
        wrow[i] = (r >> 4) * Hv + c0 + (r & 15);
    }

    // ---- hoist step-invariant Whh slice into registers (16 x float4) ----
    float4 whr[4][4];
    #pragma unroll
    for (int j = 0; j < 4; ++j)
        #pragma unroll
        for (int i = 0; i < 4; ++i)
            whr[j][i] = *(const float4*)(Whh + (size_t)wrow[i] * Dv
                                             + (j * 32 + kseg) * 4);

    // ---- per-thread pointwise state (threads 0..127: ib = tid>>4, cell = tid&15) ----
    const int pw_ib   = tid >> 4;    // 0..7  (valid when tid<128)
    const int pw_cell = tid & 15;    // 0..15
    float cst_r = 0.0f;
    int   len_r = 0;
    if (tid < 128) len_r = lengths[b0 + pw_ib];

    for (int s = 0; s < Tv; ++s) {
        const int t = dir ? (Tv - 1 - s) : s;

        // ---- 1. stage x_t: 8 batches x 512 (2 float4 per thread) ----
        #pragma unroll
        for (int j = 0; j < 2; ++j) {
            int F  = tid + j * 512;           // 0..1023 f4-slots
            int bl = F >> 7, cf = F & 127;
            *(float4*)(xb + bl * XS + cf * 4) =
                *(const float4*)(x + ((size_t)(b0 + bl) * Tv + t) * Dv + cf * 4);
        }
        __syncthreads();   // [A] xb ready

        // ---- 2. x-part GEMM: acc[4 rows][8 batches] ----
        float acc[4][8];
        #pragma unroll
        for (int i = 0; i < 4; ++i)
            #pragma unroll
            for (int ib = 0; ib < 8; ++ib) acc[i][ib] = 0.0f;

        #pragma unroll
        for (int j = 0; j < 4; ++j) {
            const int col = (j * 32 + kseg) * 4;    // float col 0..511
            float4 wv[4];
            #pragma unroll
            for (int i = 0; i < 4; ++i)
                wv[i] = *(const float4*)(Wih + (size_t)wrow[i] * Dv + col);
            float4 xv[8];
            #pragma unroll
            for (int ib = 0; ib < 8; ++ib)
                xv[ib] = *(const float4*)(xb + ib * XS + col);
            #pragma unroll
            for (int i = 0; i < 4; ++i)
                #pragma unroll
                for (int ib = 0; ib < 8; ++ib)
                    acc[i][ib] += wv[i].x * xv[ib].x + wv[i].y * xv[ib].y
                                + wv[i].z * xv[ib].z + wv[i].w * xv[ib].w;
        }

        // ---- 3. WAIT: 32 threads poll 32 packed slots (2 lines/round) ----
        if (s > 0 && tid < 32) {
            const unsigned int tgt = (unsigned int)s;
            const unsigned int* sl = cnt + (size_t)group * 64 + tid;
            while (__hip_atomic_load(sl, __ATOMIC_RELAXED,
                                     __HIP_MEMORY_SCOPE_AGENT) < tgt)
                __builtin_amdgcn_s_sleep(1);
        }
        __syncthreads();   // [B] barrier passed

        // ---- 4. stage h_{s-1} from out (fresh addresses -> L2 miss -> LLC) ----
        if (s == 0) {
            #pragma unroll
            for (int j = 0; j < 2; ++j) {
                int F  = tid + j * 512;
                int bl = F >> 7, cf = F & 127;
                *(float4*)(hu + bl * HS + cf * 4) = make_float4(0.f, 0.f, 0.f, 0.f);
            }
        } else {
            const int tp = dir ? (t + 1) : (t - 1);
            #pragma unroll
            for (int j = 0; j < 2; ++j) {
                int F  = tid + j * 512;
                int bl = F >> 7, cf = F & 127;
                *(float4*)(hu + bl * HS + cf * 4) =
                    *(const float4*)(out + ((size_t)(b0 + bl) * Tv + tp) * (2 * Hv)
                                         + dir * Hv + cf * 4);
            }
        }
        __syncthreads();   // [C] hu ready

        // hold-value for masked batches (read before hu is reused as partial)
        float hpv = 0.0f;
        if (tid < 128) hpv = hu[pw_ib * HS + c0 + pw_cell];

        // ---- 5. h-part GEMM: pure LDS + register weights ----
        #pragma unroll
        for (int j = 0; j < 4; ++j) {
            const int col = (j * 32 + kseg) * 4;
            float4 hv[8];
            #pragma unroll
            for (int ib = 0; ib < 8; ++ib)
                hv[ib] = *(const float4*)(hu + ib * HS + col);
            #pragma unroll
            for (int i = 0; i < 4; ++i)
                #pragma unroll
                for (int ib = 0; ib < 8; ++ib)
                    acc[i][ib] += whr[j][i].x * hv[ib].x + whr[j][i].y * hv[ib].y
                                + whr[j][i].z * hv[ib].z + whr[j][i].w * hv[ib].w;
        }
        __syncthreads();   // [D] hu reads + hpv done; alias as partial[512][33]

        // ---- 6. partial dump: part[(row*8+ib)][kseg], pad 33 ----
        float* part = hu;
        #pragma unroll
        for (int i = 0; i < 4; ++i) {
            const int r = pos * 4 + i;
            #pragma unroll
            for (int ib = 0; ib < 8; ++ib)
                part[(r * 8 + ib) * 33 + kseg] = acc[i][ib];
        }
        __syncthreads();   // [E]

        // ---- 7. final reduce + bias -> gates[row][ib] ----
        {
            const float* pr = part + tid * 33;   // row*8+ib == tid
            float s0 = 0.f, s1 = 0.f, s2 = 0.f, s3 = 0.f;
            #pragma unroll
            for (int m = 0; m < 32; m += 4) {
                s0 += pr[m + 0]; s1 += pr[m + 1]; s2 += pr[m + 2]; s3 += pr[m + 3];
            }
            gates[(tid >> 3) * 9 + (tid & 7)] =
                ((s0 + s1) + (s2 + s3)) + bias_s[tid >> 3];
        }
        __syncthreads();   // [F] gates ready

        // ---- 8. pointwise (128 thr), publish full 64B lines via sc1 ----
        if (tid < 128) {
            float gi = sigmf_(gates[( 0 + pw_cell) * 9 + pw_ib]);
            float gf = sigmf_(gates[(16 + pw_cell) * 9 + pw_ib]);
            float gg = tanhf_(gates[(32 + pw_cell) * 9 + pw_ib]);
            float go = sigmf_(gates[(48 + pw_cell) * 9 + pw_ib]);
            float cn = gf * cst_r + gi * gg;
            float hn = go * tanhf_(cn);
            const bool v = (t < len_r);
            float ho = v ? hn : hpv;
            cst_r = v ? cn : cst_r;
            // consecutive tid -> consecutive cell -> 64B-line coalesced
            __hip_atomic_store(out + ((size_t)(b0 + pw_ib) * Tv + t) * (2 * Hv)
                                   + dir * Hv + c0 + pw_cell,
                               ho, __ATOMIC_RELAXED, __HIP_MEMORY_SCOPE_AGENT);
        }
        __syncthreads();   // [G] all publish stores drained (vmcnt 0 at barrier)

        // ---- 9. ARRIVE: plain release store to own packed slot ----
        if (tid == 0)
            __hip_atomic_store(myslot, (unsigned int)(s + 1),
                               __ATOMIC_RELEASE, __HIP_MEMORY_SCOPE_AGENT);
    }
}

// ---------------- fallback: R10 kernel (unchanged, correct, slow) ----------------
__global__ __launch_bounds__(1024, 1) void bilstm_simple(
    const float* __restrict__ x,
    const int* __restrict__ lengths,
    const float* __restrict__ Wih_f, const float* __restrict__ Whh_f,
    const float* __restrict__ bih_f, const float* __restrict__ bhh_f,
    const float* __restrict__ Wih_b, const float* __restrict__ Whh_b,
    const float* __restrict__ bih_b, const float* __restrict__ bhh_b,
    float* __restrict__ out)
{
    __shared__ float xh[Dv + Hv];
    __shared__ float cst[Hv];
    __shared__ float gates[4 * Hv];
    __shared__ float bias[4 * Hv];

    const int tid  = threadIdx.x;
    const int wave = tid >> 6;
    const int lane = tid & 63;
    const int dir  = blockIdx.x >> 5;
    const int b    = blockIdx.x & 31;

    const float* Wih = dir ? Wih_b : Wih_f;
    const float* Whh = dir ? Whh_b : Whh_f;
    const float* bih = dir ? bih_b : bih_f;
    const float* bhh = dir ? bhh_b : bhh_f;

    for (int i = tid; i < 4 * Hv; i += 1024) bias[i] = bih[i] + bhh[i];
    for (int i = tid; i < Hv; i += 1024) { xh[Dv + i] = 0.f; cst[i] = 0.f; }
    const int len = lengths[b];

    const float* Wbase = (lane < 32) ? Wih : Whh;
    const int koff = (lane & 31) * 16;

    for (int s = 0; s < Tv; ++s) {
        const int t = dir ? (Tv - 1 - s) : s;
        __syncthreads();
        for (int i = tid; i < Dv; i += 1024)
            xh[i] = x[((size_t)b * Tv + t) * Dv + i];
        __syncthreads();

        float4 xr0 = *(const float4*)(xh + lane * 16 + 0);
        float4 xr1 = *(const float4*)(xh + lane * 16 + 4);
        float4 xr2 = *(const float4*)(xh + lane * 16 + 8);
        float4 xr3 = *(const float4*)(xh + lane * 16 + 12);

        #pragma unroll 4
        for (int rr = 0; rr < 128; ++rr) {
            const int row = wave * 128 + rr;
            const float4* wr = (const float4*)(Wbase + (size_t)row * 512 + koff);
            const float4 w0 = wr[0], w1 = wr[1], w2 = wr[2], w3 = wr[3];
            float acc = w0.x * xr0.x + w0.y * xr0.y + w0.z * xr0.z + w0.w * xr0.w
                      + w1.x * xr1.x + w1.y * xr1.y + w1.z * xr1.z + w1.w * xr1.w
                      + w2.x * xr2.x + w2.y * xr2.y + w2.z * xr2.z + w2.w * xr2.w
                      + w3.x * xr3.x + w3.y * xr3.y + w3.z * xr3.z + w3.w * xr3.w;
            #pragma unroll
            for (int off = 32; off > 0; off >>= 1)
                acc += __shfl_xor(acc, off, 64);
            if (lane == 0) gates[row] = acc;
        }
        __syncthreads();

        if (tid < Hv) {
            const int cc = tid;
            const float gi = sigmf_(gates[0 * Hv + cc] + bias[0 * Hv + cc]);
            const float gf = sigmf_(gates[1 * Hv + cc] + bias[1 * Hv + cc]);
            const float gg = tanhf_(gates[2 * Hv + cc] + bias[2 * Hv + cc]);
            const float go = sigmf_(gates[3 * Hv + cc] + bias[3 * Hv + cc]);
            const float cn = gf * cst[cc] + gi * gg;
            const float hn = go * tanhf_(cn);
            const bool v = (t < len);
            const float hnew = v ? hn : xh[Dv + cc];
            cst[cc] = v ? cn : cst[cc];
            xh[Dv + cc] = hnew;
            out[((size_t)b * Tv + t) * (2 * Hv) + dir * Hv + cc] = hnew;
        }
    }
}

extern "C" void kernel_launch(void* const* d_in, const int* in_sizes, int n_in,
                              void* d_out, int out_size, void* d_ws, size_t ws_size,
                              hipStream_t stream) {
    (void)out_size;

    const void *xv, *len_p, *Wihf, *Whhf, *bihf, *bhhf, *Wihb, *Whhb, *bihb, *bhhb;
    if (n_in == 10 && in_sizes[9] == 8388608 && in_sizes[8] == 32) {
        // alphabetical pytree order fallback
        Whhb = d_in[0]; Whhf = d_in[1]; Wihb = d_in[2]; Wihf = d_in[3];
        bhhb = d_in[4]; bhhf = d_in[5]; bihb = d_in[6]; bihf = d_in[7];
        len_p = d_in[8]; xv = d_in[9];
    } else {
        // documented dict order
        xv = d_in[0]; len_p = d_in[1];
        Wihf = d_in[2]; Whhf = d_in[3]; bihf = d_in[4]; bhhf = d_in[5];
        Wihb = d_in[6]; Whhb = d_in[7]; bihb = d_in[8]; bhhb = d_in[9];
    }

    const float* xf  = (const float*)xv;
    const int*   lp  = (const int*)len_p;
    const float* wif = (const float*)Wihf;  const float* whf = (const float*)Whhf;
    const float* bif = (const float*)bihf;  const float* bhf = (const float*)bhhf;
    const float* wib = (const float*)Wihb;  const float* whb = (const float*)Whhb;
    const float* bib = (const float*)bihb;  const float* bhb = (const float*)bhhb;
    float* outp = (float*)d_out;
    unsigned int* cntp = (unsigned int*)d_ws;

    if (ws_size >= 8 * 64 * sizeof(unsigned int)) {   // 2 KB of slots
        void* args[12] = { &xf, &lp, &wif, &whf, &bif, &bhf,
                           &wib, &whb, &bib, &bhb, &outp, &cntp };
        hipError_t e = hipLaunchCooperativeKernel((const void*)bilstm_coop5,
                                                  dim3(256), dim3(512),
                                                  args, 0, stream);
        if (e == hipSuccess) return;
    }

    // fallback: R10 kernel
    bilstm_simple<<<dim3(64), dim3(1024), 0, stream>>>(
        xf, lp, wif, whf, bif, bhf, wib, whb, bib, bhb, outp);
}